// Round 5
// baseline (1137.576 us; speedup 1.0000x reference)
//
#include <hip/hip_runtime.h>

// DeepTreeLSTM on MI355X (gfx950). Inputs fp32 (verified R3); dtype probe kept.
// Tree: 511 nodes, level d has 2^d nodes. h level-major: base_d = 256*(2^d-1)*256.
//
// Level math: (h_2p + h_2p+1) @ U == pair-sum of child-row GEMM outputs. One GEMM
// over 128 child rows x {F,I,O,U} weight groups; MFMA C-layout puts child pairs
// and all 4 groups in the same lane -> whole LSTM cell epilogue is in-register.
//
// Workspace:
//   h_all  bf16 [0,           66,977,792)
//   cbufA  bf16 [66,977,792, 100,532,224)   c for even levels (8,6,4,2,0)
//   cbufB  bf16 [100,532,224,117,309,440)   c for odd levels (7,5,3,1)
//   arena  bf16 [117,309,440,118,401,928)   converted weights/biases/emo
//   flag   int  [118,401,928,118,401,932)
//   x2     fp32 [118,401,936,118,958,992)
//   xleaf  bf16 [118,959,104,152,513,536)   cast leaf X (only if ws_size allows)

typedef __attribute__((ext_vector_type(8))) short short8;
typedef __attribute__((ext_vector_type(4))) float f32x4;

#define HB 256
#define BASE8 16711680   // 256*255*256

#define A_WIOU 0
#define A_UIOU 196608
#define A_BIOU 393216
#define A_UFW  393984
#define A_UFB  459520
#define A_WIN  459776
#define A_BIN  529408
#define A_WMID 529536
#define A_BMID 537728
#define A_WOUT 537792
#define A_BOUT 538048
#define A_EMO  538052
#define A_TOT  546244

__device__ __forceinline__ float b2f(short s){
  union { unsigned u; float f; } v; v.u = ((unsigned)(unsigned short)s) << 16; return v.f;
}
__device__ __forceinline__ short f2b(float f){
  union { float f; unsigned u; } v; v.f = f;
  unsigned r = v.u + 0x7fffu + ((v.u >> 16) & 1u);   // RNE
  return (short)(unsigned short)(r >> 16);
}
__device__ __forceinline__ float fsig(float x){ return 1.f / (1.f + __expf(-x)); }
__device__ __forceinline__ float ftanh(float x){
  x = fminf(fmaxf(x, -10.f), 10.f);
  float e = __expf(2.f * x);
  return (e - 1.f) / (e + 1.f);
}

// LDS A-tile: 128 rows x 256 k, XOR-swizzled 8-short groups, exactly 64 KB.
// elem (row, k) -> short index row*256 + (((k>>3) ^ (row & 31)) << 3) + (k & 7)
__device__ __forceinline__ int swz(int row, int g){  // g = k>>3, 16B-group index
  return row * 256 + (((g ^ (row & 31)) & 31) << 3);
}

__device__ __forceinline__ short8 ldfrag(const void* base, size_t eoff, bool isf){
  if (isf){
    const float* p = (const float*)base + eoff;
    const float4 u = *(const float4*)p;
    const float4 w = *(const float4*)(p + 4);
    short8 r;
    r[0]=f2b(u.x); r[1]=f2b(u.y); r[2]=f2b(u.z); r[3]=f2b(u.w);
    r[4]=f2b(w.x); r[5]=f2b(w.y); r[6]=f2b(w.z); r[7]=f2b(w.w);
    return r;
  }
  return *(const short8*)((const short*)base + eoff);
}

// ---------------- dtype probe ------------------------------------------------------------
__global__ __launch_bounds__(256)
void probe_kernel(const void* __restrict__ X, int* __restrict__ flag)
{
  __shared__ int sh[256];
  const int t = threadIdx.x;
  const unsigned short* p = (const unsigned short*)X;
  int cnt = 0;
  #pragma unroll
  for (int k = 0; k < 16; ++k){
    unsigned e = (p[t * 16 + k] >> 7) & 0xFFu;
    cnt += (e >= 0xC0u);
  }
  sh[t] = cnt; __syncthreads();
  for (int s = 128; s > 0; s >>= 1){ if (t < s) sh[t] += sh[t + s]; __syncthreads(); }
  if (t == 0) *flag = (sh[0] >= 16) ? 1 : 0;
}

// ---------------- convert params into bf16 arena -----------------------------------------
__global__ __launch_bounds__(256)
void conv_kernel(const void* s0, const void* s1, const void* s2, const void* s3,
                 const void* s4, const void* s5, const void* s6, const void* s7,
                 const void* s8, const void* s9, const void* s10, const void* s11,
                 short* __restrict__ arena, const int* __restrict__ flag)
{
  const int i = blockIdx.x * 256 + threadIdx.x;
  if (i >= A_TOT) return;
  const int bounds[13] = {A_WIOU, A_UIOU, A_BIOU, A_UFW, A_UFB, A_WIN, A_BIN,
                          A_WMID, A_BMID, A_WOUT, A_BOUT, A_EMO, A_TOT};
  const void* sp[12] = {s0,s1,s2,s3,s4,s5,s6,s7,s8,s9,s10,s11};
  int seg = 0;
  #pragma unroll
  for (int k = 1; k < 12; ++k) if (i >= bounds[k]) seg = k;
  const int j = i - bounds[seg];
  const float v = (*flag) ? ((const float*)sp[seg])[j] : b2f(((const short*)sp[seg])[j]);
  arena[i] = f2b(v);
}

// ---------------- cast leaf X -> dense bf16 [65536 x 256] --------------------------------
__global__ __launch_bounds__(256)
void cast_kernel(const void* __restrict__ X, const int* __restrict__ flag,
                 short* __restrict__ xleaf)
{
  const int e0 = (blockIdx.x * 256 + threadIdx.x) * 8;
  const int r = e0 >> 8, col = e0 & 255;
  const size_t src = ((size_t)(r >> 8) * 511 + 255 + (r & 255)) * HB + col;
  short8 v;
  if (*flag){
    const float* p = (const float*)X + src;
    const float4 u = *(const float4*)p;
    const float4 w = *(const float4*)(p + 4);
    v[0]=f2b(u.x); v[1]=f2b(u.y); v[2]=f2b(u.z); v[3]=f2b(u.w);
    v[4]=f2b(w.x); v[5]=f2b(w.y); v[6]=f2b(w.z); v[7]=f2b(w.w);
  } else {
    v = *(const short8*)((const short*)X + src);
  }
  *(short8*)(xleaf + e0) = v;
}

// ---------------- leaf v3: LDS-staged A, in-lane gates -----------------------------------
// grid (512), block 256. Block: 128 rows; 4 col-slices of 64 looped inside.
// Wave w: 16 cols (cb + w*16 + l15) x {I,O,U}; acc[8 rowtiles][3].
__global__ __launch_bounds__(256, 2)
void leaf_lds(const short* __restrict__ xleaf, const short* __restrict__ arena,
              short* __restrict__ hall, short* __restrict__ cout)
{
  __shared__ short At[32768];
  const int t = threadIdx.x, lane = t & 63, w = t >> 6;
  const int l15 = lane & 15, quad = lane >> 4;
  const size_t rowbase = (size_t)128 * blockIdx.x;

  // stage 128 rows x 256 k
  {
    const int l = lane;
    #pragma unroll
    for (int i = 0; i < 16; ++i){
      const int c = i * 4 + w;                 // chunk = 2 rows
      const int row = 2 * c + (l >> 5);
      const int g = l & 31;
      *(short8*)&At[swz(row, g)] =
          *(const short8*)(xleaf + (rowbase + 2 * c) * HB + (size_t)l * 8);
    }
  }
  __syncthreads();

  for (int s = 0; s < 4; ++s){
    const int col = s * 64 + w * 16 + l15;
    const short* pbI = arena + A_WIOU + (size_t)col * HB + quad * 8;
    const short* pbO = arena + A_WIOU + (size_t)(256 + col) * HB + quad * 8;
    const short* pbU = arena + A_WIOU + (size_t)(512 + col) * HB + quad * 8;

    f32x4 acc[8][3];
    #pragma unroll
    for (int rt = 0; rt < 8; ++rt)
      #pragma unroll
      for (int g = 0; g < 3; ++g) acc[rt][g] = (f32x4){0.f,0.f,0.f,0.f};

    #pragma unroll
    for (int k = 0; k < HB; k += 32){
      short8 bI = *(const short8*)(pbI + k);
      short8 bO = *(const short8*)(pbO + k);
      short8 bU = *(const short8*)(pbU + k);
      #pragma unroll
      for (int rt = 0; rt < 8; ++rt){
        const int row = rt * 16 + l15;
        short8 a = *(const short8*)&At[swz(row, (k >> 3) + quad)];
        acc[rt][0] = __builtin_amdgcn_mfma_f32_16x16x32_bf16(a, bI, acc[rt][0], 0, 0, 0);
        acc[rt][1] = __builtin_amdgcn_mfma_f32_16x16x32_bf16(a, bO, acc[rt][1], 0, 0, 0);
        acc[rt][2] = __builtin_amdgcn_mfma_f32_16x16x32_bf16(a, bU, acc[rt][2], 0, 0, 0);
      }
    }

    const float bi = b2f(arena[A_BIOU + col]);
    const float bo = b2f(arena[A_BIOU + 256 + col]);
    const float bu = b2f(arena[A_BIOU + 512 + col]);
    #pragma unroll
    for (int rt = 0; rt < 8; ++rt){
      const f32x4 vi = acc[rt][0], vo = acc[rt][1], vu = acc[rt][2];
      #pragma unroll
      for (int r = 0; r < 4; ++r){
        const size_t row = rowbase + rt * 16 + quad * 4 + r;
        const float ig = fsig(vi[r] + bi);
        const float og = fsig(vo[r] + bo);
        const float ug = ftanh(vu[r] + bu);
        const float cv = ig * ug;               // c_in = 0
        const float hv = og * ftanh(cv);
        const size_t o = row * HB + col;
        hall[BASE8 + o] = f2b(hv);
        cout[o] = f2b(cv);
      }
    }
  }
}

// ---------------- leaf fallback (dual-dtype, reads X in place) ---------------------------
__global__ __launch_bounds__(256)
void leaf_any(const void* __restrict__ X, const short* __restrict__ arena,
              const int* __restrict__ flag,
              short* __restrict__ hall, short* __restrict__ cout)
{
  const bool isf = (*flag) != 0;
  const short* Wiou = arena + A_WIOU;
  const short* biou = arena + A_BIOU;
  const int lane = threadIdx.x & 63;
  const int w    = threadIdx.x >> 6;
  const int l15  = lane & 15;
  const int quad = lane >> 4;
  const int row0 = blockIdx.x * 64 + (w >> 1) * 32;
  const int gc0  = blockIdx.y * 64 + (w & 1) * 32;

  const int rA = row0 + l15;
  const int rB = rA + 16;
  const size_t offA = (size_t)((rA >> 8) * 511 + 255 + (rA & 255)) * HB + quad * 8;
  const size_t offB = (size_t)((rB >> 8) * 511 + 255 + (rB & 255)) * HB + quad * 8;

  const short* pb[3][2];
  #pragma unroll
  for (int g = 0; g < 3; ++g)
    #pragma unroll
    for (int t = 0; t < 2; ++t)
      pb[g][t] = Wiou + (size_t)(g * 256 + gc0 + t * 16 + l15) * HB + quad * 8;

  f32x4 acc[2][3][2];
  #pragma unroll
  for (int rt = 0; rt < 2; ++rt)
    #pragma unroll
    for (int g = 0; g < 3; ++g)
      #pragma unroll
      for (int t = 0; t < 2; ++t)
        acc[rt][g][t] = (f32x4){0.f, 0.f, 0.f, 0.f};

  for (int k = 0; k < HB; k += 32){
    short8 a0 = ldfrag(X, offA + k, isf);
    short8 a1 = ldfrag(X, offB + k, isf);
    #pragma unroll
    for (int g = 0; g < 3; ++g)
      #pragma unroll
      for (int t = 0; t < 2; ++t){
        short8 bfr = *(const short8*)(pb[g][t] + k);
        acc[0][g][t] = __builtin_amdgcn_mfma_f32_16x16x32_bf16(a0, bfr, acc[0][g][t], 0, 0, 0);
        acc[1][g][t] = __builtin_amdgcn_mfma_f32_16x16x32_bf16(a1, bfr, acc[1][g][t], 0, 0, 0);
      }
  }

  #pragma unroll
  for (int t = 0; t < 2; ++t){
    const int col = gc0 + t * 16 + l15;
    const float bi = b2f(biou[col]);
    const float bo = b2f(biou[256 + col]);
    const float bu = b2f(biou[512 + col]);
    #pragma unroll
    for (int rt = 0; rt < 2; ++rt){
      const int rbase = row0 + rt * 16 + quad * 4;
      const f32x4 vi = acc[rt][0][t];
      const f32x4 vo = acc[rt][1][t];
      const f32x4 vu = acc[rt][2][t];
      #pragma unroll
      for (int r = 0; r < 4; ++r){
        const int row = rbase + r;
        const float ig = fsig(vi[r] + bi);
        const float og = fsig(vo[r] + bo);
        const float ug = ftanh(vu[r] + bu);
        const float cv = ig * ug;
        const float hv = og * ftanh(cv);
        const size_t o = (size_t)row * HB + col;
        hall[BASE8 + o] = f2b(hv);
        cout[o] = f2b(cv);
      }
    }
  }
}

// ---------------- level v3: child-row GEMM vs {F,I,O,U}, in-lane pair-sum epilogue -------
// grid (nP/64, 2), block 256. Block: 128 child rows (64 parents); 2 col-slices of 64.
// Wave w: 16 cols x 4 groups; acc[8 rowtiles][4]. Child pairs (2p,2p+1) are reg
// pairs {0,1},{2,3} of the same lane -> f*c aggregate and iou pair-sum in-register.
__global__ __launch_bounds__(256, 2)
void level_lds(const short* __restrict__ hch, const short* __restrict__ cch,
               const short* __restrict__ arena,
               short* __restrict__ hout, short* __restrict__ cout)
{
  __shared__ short At[32768];
  const int t = threadIdx.x, lane = t & 63, w = t >> 6;
  const int l15 = lane & 15, quad = lane >> 4;
  const size_t rowbase = (size_t)128 * blockIdx.x;    // child rows
  const int pbase = 64 * blockIdx.x;                  // parent rows

  {
    const int l = lane;
    #pragma unroll
    for (int i = 0; i < 16; ++i){
      const int c = i * 4 + w;
      const int row = 2 * c + (l >> 5);
      const int g = l & 31;
      *(short8*)&At[swz(row, g)] =
          *(const short8*)(hch + (rowbase + 2 * c) * HB + (size_t)l * 8);
    }
  }
  __syncthreads();

  for (int s = 0; s < 2; ++s){
    const int col = blockIdx.y * 128 + s * 64 + w * 16 + l15;
    const short* pbF = arena + A_UFW  + (size_t)col * HB + quad * 8;
    const short* pbI = arena + A_UIOU + (size_t)col * HB + quad * 8;
    const short* pbO = arena + A_UIOU + (size_t)(256 + col) * HB + quad * 8;
    const short* pbU = arena + A_UIOU + (size_t)(512 + col) * HB + quad * 8;

    f32x4 acc[8][4];
    #pragma unroll
    for (int rt = 0; rt < 8; ++rt)
      #pragma unroll
      for (int g = 0; g < 4; ++g) acc[rt][g] = (f32x4){0.f,0.f,0.f,0.f};

    #pragma unroll
    for (int k = 0; k < HB; k += 32){
      short8 bF = *(const short8*)(pbF + k);
      short8 bI = *(const short8*)(pbI + k);
      short8 bO = *(const short8*)(pbO + k);
      short8 bU = *(const short8*)(pbU + k);
      #pragma unroll
      for (int rt = 0; rt < 8; ++rt){
        const int row = rt * 16 + l15;
        short8 a = *(const short8*)&At[swz(row, (k >> 3) + quad)];
        acc[rt][0] = __builtin_amdgcn_mfma_f32_16x16x32_bf16(a, bF, acc[rt][0], 0, 0, 0);
        acc[rt][1] = __builtin_amdgcn_mfma_f32_16x16x32_bf16(a, bI, acc[rt][1], 0, 0, 0);
        acc[rt][2] = __builtin_amdgcn_mfma_f32_16x16x32_bf16(a, bO, acc[rt][2], 0, 0, 0);
        acc[rt][3] = __builtin_amdgcn_mfma_f32_16x16x32_bf16(a, bU, acc[rt][3], 0, 0, 0);
      }
    }

    const float bf = b2f(arena[A_UFB + col]);
    const float bi = b2f(arena[A_BIOU + col]);
    const float bo = b2f(arena[A_BIOU + 256 + col]);
    const float bu = b2f(arena[A_BIOU + 512 + col]);
    #pragma unroll
    for (int rt = 0; rt < 8; ++rt){
      const size_t crow = (rowbase + rt * 16 + quad * 4) * HB + col;
      const float c0 = b2f(cch[crow]);
      const float c1 = b2f(cch[crow + HB]);
      const float c2 = b2f(cch[crow + 2 * HB]);
      const float c3 = b2f(cch[crow + 3 * HB]);
      const f32x4 dF = acc[rt][0], dI = acc[rt][1], dO = acc[rt][2], dU = acc[rt][3];
      const float ca0 = fsig(dF[0] + bf) * c0 + fsig(dF[1] + bf) * c1;
      const float ca1 = fsig(dF[2] + bf) * c2 + fsig(dF[3] + bf) * c3;
      const int p0 = pbase + rt * 8 + quad * 2;
      {
        const float ig = fsig(dI[0] + dI[1] + bi);
        const float og = fsig(dO[0] + dO[1] + bo);
        const float ug = ftanh(dU[0] + dU[1] + bu);
        const float cv = ig * ug + ca0;
        const float hv = og * ftanh(cv);
        const size_t o = (size_t)p0 * HB + col;
        hout[o] = f2b(hv); cout[o] = f2b(cv);
      }
      {
        const float ig = fsig(dI[2] + dI[3] + bi);
        const float og = fsig(dO[2] + dO[3] + bo);
        const float ug = ftanh(dU[2] + dU[3] + bu);
        const float cv = ig * ug + ca1;
        const float hv = og * ftanh(cv);
        const size_t o = (size_t)(p0 + 1) * HB + col;
        hout[o] = f2b(hv); cout[o] = f2b(cv);
      }
    }
  }
}

// ---------------- final reduction -> x2 (fp32, B x 544) ----------------------------------
__global__ __launch_bounds__(1024)
void reduce_kernel(const short* __restrict__ hall, const short* __restrict__ arena,
                   float* __restrict__ x2)
{
  __shared__ float sums[32][256];
  const int b = blockIdx.x, t = threadIdx.x;
  const int g = t >> 5, cb = (t & 31) * 8;
  float s[8];
  #pragma unroll
  for (int e = 0; e < 8; ++e) s[e] = 0.f;
  size_t base = 0;
  for (int d = 0; d <= 8; ++d){
    const int m = 1 << d;
    for (int j = g; j < m; j += 32){
      const short8 v = *(const short8*)(hall + base + (size_t)(b * m + j) * HB + cb);
      #pragma unroll
      for (int e = 0; e < 8; ++e) s[e] += b2f(v[e]);
    }
    base += (size_t)256 * m * HB;
  }
  #pragma unroll
  for (int e = 0; e < 8; ++e) sums[g][cb + e] = s[e];
  __syncthreads();
  if (t < 256){
    float tot = 0.f;
    #pragma unroll
    for (int gg = 0; gg < 32; ++gg) tot += sums[gg][t];
    const float head = b2f(hall[(size_t)b * HB + t]);
    const float last = b2f(hall[(size_t)BASE8 + ((size_t)b * 256 + 255) * HB + t]);
    x2[(size_t)b * 544 + t]       = head;
    x2[(size_t)b * 544 + 256 + t] = (tot - head - last) * (1.f / 509.f);
  } else if (t < 288){
    x2[(size_t)b * 544 + 512 + (t - 256)] = b2f(arena[A_EMO + b * 32 + (t - 256)]);
  }
}

// ---------------- head MLP: 544 -> 128 -> 64 -> 4 ----------------------------------------
__global__ __launch_bounds__(256)
void head_kernel(const float* __restrict__ x2, const short* __restrict__ arena,
                 const int* __restrict__ flag, void* __restrict__ outv)
{
  __shared__ float sx[544];
  __shared__ float sy1[128];
  __shared__ float sy2[64];
  const int b = blockIdx.x, t = threadIdx.x;
  for (int i = t; i < 544; i += 256) sx[i] = x2[(size_t)b * 544 + i];
  __syncthreads();
  if (t < 128){
    float a = b2f(arena[A_BIN + t]);
    const short* wr = arena + A_WIN + (size_t)t * 544;
    for (int k = 0; k < 544; ++k) a += sx[k] * b2f(wr[k]);
    sy1[t] = fmaxf(a, 0.f);
  }
  __syncthreads();
  if (t < 64){
    float a = b2f(arena[A_BMID + t]);
    const short* wr = arena + A_WMID + (size_t)t * 128;
    for (int k = 0; k < 128; ++k) a += sy1[k] * b2f(wr[k]);
    sy2[t] = fmaxf(a, 0.f);
  }
  __syncthreads();
  if (t < 4){
    float a = b2f(arena[A_BOUT + t]);
    const short* wr = arena + A_WOUT + (size_t)t * 64;
    for (int k = 0; k < 64; ++k) a += sy2[k] * b2f(wr[k]);
    const float sg = fsig(a);
    if (*flag) ((float*)outv)[(size_t)b * 4 + t] = sg;
    else       ((short*)outv)[(size_t)b * 4 + t] = f2b(sg);
  }
}

extern "C" void kernel_launch(void* const* d_in, const int* in_sizes, int n_in,
                              void* d_out, int out_size, void* d_ws, size_t ws_size,
                              hipStream_t stream)
{
  (void)in_sizes; (void)n_in; (void)out_size;
  const void* X    = d_in[0];
  const void* emo  = d_in[3];
  const void* Wiou = d_in[4];
  const void* Uiou = d_in[5];
  const void* biou = d_in[6];
  const void* Ufw  = d_in[7];
  const void* Ufb  = d_in[8];
  const void* Win  = d_in[9];
  const void* bin  = d_in[10];
  const void* Wmid = d_in[11];
  const void* bmid = d_in[12];
  const void* Wout = d_in[13];
  const void* bout = d_in[14];

  char* ws = (char*)d_ws;
  short* h_all = (short*)ws;
  short* cbufA = (short*)(ws + 66977792);
  short* cbufB = (short*)(ws + 100532224);
  short* arena = (short*)(ws + 117309440);
  int*   flag  = (int*)  (ws + 118401928);
  float* x2    = (float*)(ws + 118401936);
  short* xleaf = (short*)(ws + 118959104);
  const bool can_cast = ws_size >= 152513536u;

  dim3 blk(256);

  probe_kernel<<<dim3(1), blk, 0, stream>>>(X, flag);
  conv_kernel<<<dim3((A_TOT + 255) / 256), blk, 0, stream>>>(
      Wiou, Uiou, biou, Ufw, Ufb, Win, bin, Wmid, bmid, Wout, bout, emo, arena, flag);

  if (can_cast){
    cast_kernel<<<dim3(8192), blk, 0, stream>>>(X, flag, xleaf);
    leaf_lds<<<dim3(512), blk, 0, stream>>>(xleaf, arena, h_all, cbufA);
  } else {
    leaf_any<<<dim3(1024, 4), blk, 0, stream>>>(X, arena, flag, h_all, cbufA);
  }

  for (int d = 7; d >= 0; --d){
    const int m = 1 << d;
    const size_t base_p  = (size_t)256 * (m - 1) * HB;
    const size_t base_ch = (size_t)256 * (2 * m - 1) * HB;
    short* csrc = ((d + 1) & 1) ? cbufB : cbufA;
    short* cdst = (d & 1) ? cbufB : cbufA;
    const int nP = 256 * m;
    level_lds<<<dim3(nP / 64, 2), blk, 0, stream>>>(h_all + base_ch, csrc, arena,
                                                    h_all + base_p, cdst);
  }

  reduce_kernel<<<dim3(256), dim3(1024), 0, stream>>>(h_all, arena, x2);
  head_kernel<<<dim3(256), blk, 0, stream>>>(x2, arena, flag, d_out);
}

// Round 6
// 884.210 us; speedup vs baseline: 1.2865x; 1.2865x over previous
//
#include <hip/hip_runtime.h>

// DeepTreeLSTM on MI355X (gfx950). Inputs fp32 (verified R3); dtype probe kept.
// Tree: 511 nodes, level d has 2^d nodes. h level-major: base_d = 256*(2^d-1)*256.
//
// Level kernel: one GEMM over 128 child rows vs {F,I,O,U} weight groups.
// MFMA 16x16x32 C-layout puts child pairs (2p,2p+1) in one lane's reg pairs and
// all 4 groups of one hidden col in the same lane -> entire LSTM cell epilogue
// in-register. A staged once in LDS (64KB, XOR swizzle), reused over 8 col
// slices; acc capped at 64 f32/lane (R5's 128 spilled -> 600MB HBM traffic).
//
// Workspace (<= ~119 MB):
//   h_all  bf16 [0,           66,977,792)
//   cbufA  bf16 [66,977,792, 100,532,224)   c for even levels (8,6,4,2,0)
//   cbufB  bf16 [100,532,224,117,309,440)   c for odd levels (7,5,3,1)
//   arena  bf16 [117,309,440,118,401,928)   converted weights/biases/emo
//   flag   int  [118,401,928,118,401,932)
//   x2     fp32 [118,401,936,118,958,992)

typedef __attribute__((ext_vector_type(8))) short short8;
typedef __attribute__((ext_vector_type(4))) float f32x4;

#define HB 256
#define BASE8 16711680   // 256*255*256

#define A_WIOU 0
#define A_UIOU 196608
#define A_BIOU 393216
#define A_UFW  393984
#define A_UFB  459520
#define A_WIN  459776
#define A_BIN  529408
#define A_WMID 529536
#define A_BMID 537728
#define A_WOUT 537792
#define A_BOUT 538048
#define A_EMO  538052
#define A_TOT  546244

__device__ __forceinline__ float b2f(short s){
  union { unsigned u; float f; } v; v.u = ((unsigned)(unsigned short)s) << 16; return v.f;
}
__device__ __forceinline__ short f2b(float f){
  union { float f; unsigned u; } v; v.f = f;
  unsigned r = v.u + 0x7fffu + ((v.u >> 16) & 1u);   // RNE
  return (short)(unsigned short)(r >> 16);
}
__device__ __forceinline__ float fsig(float x){ return 1.f / (1.f + __expf(-x)); }
__device__ __forceinline__ float ftanh(float x){
  x = fminf(fmaxf(x, -10.f), 10.f);
  float e = __expf(2.f * x);
  return (e - 1.f) / (e + 1.f);
}

// LDS A-tile: 128 rows x 256 k, XOR-swizzled 8-short groups (64 KB, conflict-free).
__device__ __forceinline__ int swz(int row, int g){   // g = k>>3
  return row * 256 + (((g ^ (row & 31)) & 31) << 3);
}

// ---------------- dtype probe ------------------------------------------------------------
__global__ __launch_bounds__(256)
void probe_kernel(const void* __restrict__ X, int* __restrict__ flag)
{
  __shared__ int sh[256];
  const int t = threadIdx.x;
  const unsigned short* p = (const unsigned short*)X;
  int cnt = 0;
  #pragma unroll
  for (int k = 0; k < 16; ++k){
    unsigned e = (p[t * 16 + k] >> 7) & 0xFFu;
    cnt += (e >= 0xC0u);
  }
  sh[t] = cnt; __syncthreads();
  for (int s = 128; s > 0; s >>= 1){ if (t < s) sh[t] += sh[t + s]; __syncthreads(); }
  if (t == 0) *flag = (sh[0] >= 16) ? 1 : 0;
}

// ---------------- convert params into bf16 arena -----------------------------------------
__global__ __launch_bounds__(256)
void conv_kernel(const void* s0, const void* s1, const void* s2, const void* s3,
                 const void* s4, const void* s5, const void* s6, const void* s7,
                 const void* s8, const void* s9, const void* s10, const void* s11,
                 short* __restrict__ arena, const int* __restrict__ flag)
{
  const int i = blockIdx.x * 256 + threadIdx.x;
  if (i >= A_TOT) return;
  const int bounds[13] = {A_WIOU, A_UIOU, A_BIOU, A_UFW, A_UFB, A_WIN, A_BIN,
                          A_WMID, A_BMID, A_WOUT, A_BOUT, A_EMO, A_TOT};
  const void* sp[12] = {s0,s1,s2,s3,s4,s5,s6,s7,s8,s9,s10,s11};
  int seg = 0;
  #pragma unroll
  for (int k = 1; k < 12; ++k) if (i >= bounds[k]) seg = k;
  const int j = i - bounds[seg];
  const float v = (*flag) ? ((const float*)sp[seg])[j] : b2f(((const short*)sp[seg])[j]);
  arena[i] = f2b(v);
}

// ---------------- leaf: 128 rows staged (fp32->bf16 inline), 8 col-slices x 3 gates ------
// grid (512), block 256 (4 waves as 2 row-halves x 2 col-halves).
// Wave: 64 rows x (16 hidden x 3 gates); acc[4 rowtiles][3] = 48 f32/lane.
__global__ __launch_bounds__(256, 2)
void leaf_kernel(const void* __restrict__ X, const short* __restrict__ arena,
                 const int* __restrict__ flag,
                 short* __restrict__ hall, short* __restrict__ cout)
{
  __shared__ short At[32768];
  const int t = threadIdx.x, lane = t & 63, w = t >> 6;
  const int l15 = lane & 15, quad = lane >> 4;
  const int rh = w >> 1, cl = w & 1;
  const int rowbase = 128 * blockIdx.x;                 // leaf-local row
  // leaf rows of one block are contiguous in X: batch = rowbase>>8, node 255+(row&255)
  const size_t grow0 = ((size_t)(rowbase >> 8) * 511 + 255 + (rowbase & 255)) * HB;
  const bool isf = (*flag) != 0;

  // stage 128 rows x 256 k (convert once per element)
  #pragma unroll
  for (int i = 0; i < 16; ++i){
    const int gi = i * 256 + t;
    const int row = gi >> 5, g = gi & 31;
    short8 v;
    if (isf){
      const float* p = (const float*)X + grow0 + (size_t)row * HB + g * 8;
      const float4 u = *(const float4*)p;
      const float4 q = *(const float4*)(p + 4);
      v[0]=f2b(u.x); v[1]=f2b(u.y); v[2]=f2b(u.z); v[3]=f2b(u.w);
      v[4]=f2b(q.x); v[5]=f2b(q.y); v[6]=f2b(q.z); v[7]=f2b(q.w);
    } else {
      v = *(const short8*)((const short*)X + grow0 + (size_t)row * HB + g * 8);
    }
    *(short8*)&At[swz(row, g)] = v;
  }
  __syncthreads();

  for (int s = 0; s < 8; ++s){
    const int colh = s * 32 + cl * 16 + l15;            // hidden col 0..255
    const short* pI = arena + A_WIOU + (size_t)colh * HB + quad * 8;
    const short* pO = pI + 65536;                       // 256*256
    const short* pU = pI + 131072;

    f32x4 acc[4][3];
    #pragma unroll
    for (int rt = 0; rt < 4; ++rt)
      #pragma unroll
      for (int g = 0; g < 3; ++g) acc[rt][g] = (f32x4){0.f,0.f,0.f,0.f};

    #pragma unroll
    for (int kk = 0; kk < 8; ++kk){
      const short8 bI = *(const short8*)(pI + kk * 32);
      const short8 bO = *(const short8*)(pO + kk * 32);
      const short8 bU = *(const short8*)(pU + kk * 32);
      #pragma unroll
      for (int rt = 0; rt < 4; ++rt){
        const int row = rh * 64 + rt * 16 + l15;
        const short8 a = *(const short8*)&At[swz(row, kk * 4 + quad)];
        acc[rt][0] = __builtin_amdgcn_mfma_f32_16x16x32_bf16(a, bI, acc[rt][0], 0, 0, 0);
        acc[rt][1] = __builtin_amdgcn_mfma_f32_16x16x32_bf16(a, bO, acc[rt][1], 0, 0, 0);
        acc[rt][2] = __builtin_amdgcn_mfma_f32_16x16x32_bf16(a, bU, acc[rt][2], 0, 0, 0);
      }
    }

    const float bi = b2f(arena[A_BIOU + colh]);
    const float bo = b2f(arena[A_BIOU + 256 + colh]);
    const float bu = b2f(arena[A_BIOU + 512 + colh]);
    #pragma unroll
    for (int rt = 0; rt < 4; ++rt){
      const f32x4 vi = acc[rt][0], vo = acc[rt][1], vu = acc[rt][2];
      #pragma unroll
      for (int r = 0; r < 4; ++r){
        const int row = rowbase + rh * 64 + rt * 16 + quad * 4 + r;
        const float ig = fsig(vi[r] + bi);
        const float og = fsig(vo[r] + bo);
        const float ug = ftanh(vu[r] + bu);
        const float cv = ig * ug;                       // c_in = 0
        const float hv = og * ftanh(cv);
        const size_t o = (size_t)row * HB + colh;
        hall[BASE8 + o] = f2b(hv);
        cout[o] = f2b(cv);
      }
    }
  }
}

// ---------------- level: 128 child rows staged, 8 col-slices x {F,I,O,U} -----------------
// grid (nP/64), block 256 (2 row-halves x 2 col-halves).
// Wave: 64 child rows x (16 hidden x 4 groups); acc[4][4] = 64 f32/lane.
__global__ __launch_bounds__(256, 2)
void level_kernel(const short* __restrict__ hch, const short* __restrict__ cch,
                  const short* __restrict__ arena,
                  short* __restrict__ hout, short* __restrict__ cout)
{
  __shared__ short At[32768];
  const int t = threadIdx.x, lane = t & 63, w = t >> 6;
  const int l15 = lane & 15, quad = lane >> 4;
  const int rh = w >> 1, cl = w & 1;
  const int rowbase = 128 * blockIdx.x;                 // child rows
  const int pbase   = 64 * blockIdx.x;                  // parent rows

  #pragma unroll
  for (int i = 0; i < 16; ++i){
    const int gi = i * 256 + t;
    const int row = gi >> 5, g = gi & 31;
    *(short8*)&At[swz(row, g)] =
        *(const short8*)(hch + (size_t)(rowbase + row) * HB + g * 8);
  }
  __syncthreads();

  for (int s = 0; s < 8; ++s){
    const int colh = s * 32 + cl * 16 + l15;
    const short* pF = arena + A_UFW  + (size_t)colh * HB + quad * 8;
    const short* pI = arena + A_UIOU + (size_t)colh * HB + quad * 8;
    const short* pO = pI + 65536;
    const short* pU = pI + 131072;

    f32x4 acc[4][4];
    #pragma unroll
    for (int rt = 0; rt < 4; ++rt)
      #pragma unroll
      for (int g = 0; g < 4; ++g) acc[rt][g] = (f32x4){0.f,0.f,0.f,0.f};

    #pragma unroll
    for (int kk = 0; kk < 8; ++kk){
      const short8 bF = *(const short8*)(pF + kk * 32);
      const short8 bI = *(const short8*)(pI + kk * 32);
      const short8 bO = *(const short8*)(pO + kk * 32);
      const short8 bU = *(const short8*)(pU + kk * 32);
      #pragma unroll
      for (int rt = 0; rt < 4; ++rt){
        const int row = rh * 64 + rt * 16 + l15;
        const short8 a = *(const short8*)&At[swz(row, kk * 4 + quad)];
        acc[rt][0] = __builtin_amdgcn_mfma_f32_16x16x32_bf16(a, bF, acc[rt][0], 0, 0, 0);
        acc[rt][1] = __builtin_amdgcn_mfma_f32_16x16x32_bf16(a, bI, acc[rt][1], 0, 0, 0);
        acc[rt][2] = __builtin_amdgcn_mfma_f32_16x16x32_bf16(a, bO, acc[rt][2], 0, 0, 0);
        acc[rt][3] = __builtin_amdgcn_mfma_f32_16x16x32_bf16(a, bU, acc[rt][3], 0, 0, 0);
      }
    }

    const float bf = b2f(arena[A_UFB + colh]);
    const float bi = b2f(arena[A_BIOU + colh]);
    const float bo = b2f(arena[A_BIOU + 256 + colh]);
    const float bu = b2f(arena[A_BIOU + 512 + colh]);
    #pragma unroll
    for (int rt = 0; rt < 4; ++rt){
      const int rloc = rh * 64 + rt * 16 + quad * 4;    // local child row, mult of 4
      const size_t crow = (size_t)(rowbase + rloc) * HB + colh;
      const float c0 = b2f(cch[crow]);
      const float c1 = b2f(cch[crow + HB]);
      const float c2 = b2f(cch[crow + 2 * HB]);
      const float c3 = b2f(cch[crow + 3 * HB]);
      const f32x4 dF = acc[rt][0], dI = acc[rt][1], dO = acc[rt][2], dU = acc[rt][3];
      const int p0 = pbase + (rloc >> 1);
      {
        const float ca = fsig(dF[0] + bf) * c0 + fsig(dF[1] + bf) * c1;
        const float ig = fsig(dI[0] + dI[1] + bi);
        const float og = fsig(dO[0] + dO[1] + bo);
        const float ug = ftanh(dU[0] + dU[1] + bu);
        const float cv = ig * ug + ca;
        const float hv = og * ftanh(cv);
        const size_t o = (size_t)p0 * HB + colh;
        hout[o] = f2b(hv); cout[o] = f2b(cv);
      }
      {
        const float ca = fsig(dF[2] + bf) * c2 + fsig(dF[3] + bf) * c3;
        const float ig = fsig(dI[2] + dI[3] + bi);
        const float og = fsig(dO[2] + dO[3] + bo);
        const float ug = ftanh(dU[2] + dU[3] + bu);
        const float cv = ig * ug + ca;
        const float hv = og * ftanh(cv);
        const size_t o = (size_t)(p0 + 1) * HB + colh;
        hout[o] = f2b(hv); cout[o] = f2b(cv);
      }
    }
  }
}

// ---------------- final reduction -> x2 (fp32, B x 544) ----------------------------------
__global__ __launch_bounds__(1024)
void reduce_kernel(const short* __restrict__ hall, const short* __restrict__ arena,
                   float* __restrict__ x2)
{
  __shared__ float sums[32][256];
  const int b = blockIdx.x, t = threadIdx.x;
  const int g = t >> 5, cb = (t & 31) * 8;
  float s[8];
  #pragma unroll
  for (int e = 0; e < 8; ++e) s[e] = 0.f;
  size_t base = 0;
  for (int d = 0; d <= 8; ++d){
    const int m = 1 << d;
    for (int j = g; j < m; j += 32){
      const short8 v = *(const short8*)(hall + base + (size_t)(b * m + j) * HB + cb);
      #pragma unroll
      for (int e = 0; e < 8; ++e) s[e] += b2f(v[e]);
    }
    base += (size_t)256 * m * HB;
  }
  #pragma unroll
  for (int e = 0; e < 8; ++e) sums[g][cb + e] = s[e];
  __syncthreads();
  if (t < 256){
    float tot = 0.f;
    #pragma unroll
    for (int gg = 0; gg < 32; ++gg) tot += sums[gg][t];
    const float head = b2f(hall[(size_t)b * HB + t]);
    const float last = b2f(hall[(size_t)BASE8 + ((size_t)b * 256 + 255) * HB + t]);
    x2[(size_t)b * 544 + t]       = head;
    x2[(size_t)b * 544 + 256 + t] = (tot - head - last) * (1.f / 509.f);
  } else if (t < 288){
    x2[(size_t)b * 544 + 512 + (t - 256)] = b2f(arena[A_EMO + b * 32 + (t - 256)]);
  }
}

// ---------------- head MLP: 544 -> 128 -> 64 -> 4 ----------------------------------------
__global__ __launch_bounds__(256)
void head_kernel(const float* __restrict__ x2, const short* __restrict__ arena,
                 const int* __restrict__ flag, void* __restrict__ outv)
{
  __shared__ float sx[544];
  __shared__ float sy1[128];
  __shared__ float sy2[64];
  const int b = blockIdx.x, t = threadIdx.x;
  for (int i = t; i < 544; i += 256) sx[i] = x2[(size_t)b * 544 + i];
  __syncthreads();
  if (t < 128){
    float a = b2f(arena[A_BIN + t]);
    const short* wr = arena + A_WIN + (size_t)t * 544;
    for (int k = 0; k < 544; ++k) a += sx[k] * b2f(wr[k]);
    sy1[t] = fmaxf(a, 0.f);
  }
  __syncthreads();
  if (t < 64){
    float a = b2f(arena[A_BMID + t]);
    const short* wr = arena + A_WMID + (size_t)t * 128;
    for (int k = 0; k < 128; ++k) a += sy1[k] * b2f(wr[k]);
    sy2[t] = fmaxf(a, 0.f);
  }
  __syncthreads();
  if (t < 4){
    float a = b2f(arena[A_BOUT + t]);
    const short* wr = arena + A_WOUT + (size_t)t * 64;
    for (int k = 0; k < 64; ++k) a += sy2[k] * b2f(wr[k]);
    const float sg = fsig(a);
    if (*flag) ((float*)outv)[(size_t)b * 4 + t] = sg;
    else       ((short*)outv)[(size_t)b * 4 + t] = f2b(sg);
  }
}

extern "C" void kernel_launch(void* const* d_in, const int* in_sizes, int n_in,
                              void* d_out, int out_size, void* d_ws, size_t ws_size,
                              hipStream_t stream)
{
  (void)in_sizes; (void)n_in; (void)out_size; (void)ws_size;
  const void* X    = d_in[0];
  const void* emo  = d_in[3];
  const void* Wiou = d_in[4];
  const void* Uiou = d_in[5];
  const void* biou = d_in[6];
  const void* Ufw  = d_in[7];
  const void* Ufb  = d_in[8];
  const void* Win  = d_in[9];
  const void* bin  = d_in[10];
  const void* Wmid = d_in[11];
  const void* bmid = d_in[12];
  const void* Wout = d_in[13];
  const void* bout = d_in[14];

  char* ws = (char*)d_ws;
  short* h_all = (short*)ws;
  short* cbufA = (short*)(ws + 66977792);
  short* cbufB = (short*)(ws + 100532224);
  short* arena = (short*)(ws + 117309440);
  int*   flag  = (int*)  (ws + 118401928);
  float* x2    = (float*)(ws + 118401936);

  dim3 blk(256);

  probe_kernel<<<dim3(1), blk, 0, stream>>>(X, flag);
  conv_kernel<<<dim3((A_TOT + 255) / 256), blk, 0, stream>>>(
      Wiou, Uiou, biou, Ufw, Ufb, Win, bin, Wmid, bmid, Wout, bout, emo, arena, flag);

  leaf_kernel<<<dim3(512), blk, 0, stream>>>(X, arena, flag, h_all, cbufA);

  for (int d = 7; d >= 0; --d){
    const int m = 1 << d;
    const size_t base_p  = (size_t)256 * (m - 1) * HB;
    const size_t base_ch = (size_t)256 * (2 * m - 1) * HB;
    short* csrc = ((d + 1) & 1) ? cbufB : cbufA;
    short* cdst = (d & 1) ? cbufB : cbufA;
    const int nP = 256 * m;
    level_kernel<<<dim3(nP / 64), blk, 0, stream>>>(h_all + base_ch, csrc, arena,
                                                    h_all + base_p, cdst);
  }

  reduce_kernel<<<dim3(256), dim3(1024), 0, stream>>>(h_all, arena, x2);
  head_kernel<<<dim3(256), blk, 0, stream>>>(x2, arena, flag, d_out);
}